// Round 3
// baseline (2581.272 us; speedup 1.0000x reference)
//
#include <hip/hip_runtime.h>

#define N_NODES 100000
#define N_EDGES 600000
#define NPAD    100096      // 782 * 128
#define NTILES  782
#define SCAN_B  98          // ceil(100000/1024)
#define EPS_F   1e-5f
#define GRIDG   256         // persistent mixed grid: 1 block (8 waves) per CU

typedef __bf16 bf16_t;
typedef __bf16 bf16x8 __attribute__((ext_vector_type(8)));
typedef __bf16 bf16x4 __attribute__((ext_vector_type(4)));
typedef float  f32x4  __attribute__((ext_vector_type(4)));

// ---------------------------------------------------------------------------
// zero deg + grid-barrier counters
__global__ __launch_bounds__(256)
void init_zero_kernel(int* __restrict__ deg, int* __restrict__ cnt)
{
    int i = blockIdx.x * 256 + threadIdx.x;
    if (i < N_NODES) deg[i] = 0;
    if (i < 32) cnt[i] = 0;
}

// ---------------------------------------------------------------------------
// Weight pre-transpose: WT[mat][n][k] = W[mat][k][n], fp32 -> bf16.
__global__ __launch_bounds__(256)
void transpose_w_kernel(const float* __restrict__ Wz, const float* __restrict__ Wf,
                        const float* __restrict__ Wm, const float* __restrict__ Wl,
                        const float* __restrict__ Wc, bf16_t* __restrict__ wt)
{
    int idx = blockIdx.x * 256 + threadIdx.x;      // < 27*16384, exact grid
    int mat = idx >> 14;
    int off = idx & 16383;
    int n = off >> 7, kk = off & 127;
    const float* src;
    if      (mat < 3)  src = Wz + mat * 16384;
    else if (mat < 12) src = Wf + (mat - 3) * 16384;
    else if (mat < 18) src = Wm + (mat - 12) * 16384;
    else if (mat < 24) src = Wl + (mat - 18) * 16384;
    else               src = Wc + (mat - 24) * 16384;
    wt[idx] = (bf16_t)src[kk * 128 + n];
}

// ---------------------------------------------------------------------------
// pre-candidates, vectorized 8 elems/thread: [se, se-hr, se*hr] as bf16
__global__ __launch_bounds__(256)
void pre_kernel(const float* __restrict__ se, const float* __restrict__ hr,
                bf16_t* __restrict__ p0, bf16_t* __restrict__ p1, bf16_t* __restrict__ p2)
{
    long i = ((long)blockIdx.x * 256 + threadIdx.x) * 8;   // grid exact: N*128/2048
    float4 a0 = *(const float4*)&se[i], a1 = *(const float4*)&se[i + 4];
    float4 b0 = *(const float4*)&hr[i], b1 = *(const float4*)&hr[i + 4];
    float av[8] = {a0.x, a0.y, a0.z, a0.w, a1.x, a1.y, a1.z, a1.w};
    float bv[8] = {b0.x, b0.y, b0.z, b0.w, b1.x, b1.y, b1.z, b1.w};
    bf16x8 o0, o1, o2;
#pragma unroll
    for (int j = 0; j < 8; ++j) {
        o0[j] = (bf16_t)av[j];
        o1[j] = (bf16_t)(av[j] - bv[j]);
        o2[j] = (bf16_t)(av[j] * bv[j]);
    }
    *(bf16x8*)&p0[i] = o0;
    *(bf16x8*)&p1[i] = o1;
    *(bf16x8*)&p2[i] = o2;
}

// ---------------------------------------------------------------------------
// CSR build
__global__ __launch_bounds__(256)
void deg_count_kernel(const int* __restrict__ dst, int* __restrict__ deg)
{
    int i = blockIdx.x * 256 + threadIdx.x;
    if (i < N_EDGES) atomicAdd(&deg[dst[i]], 1);
}

__global__ __launch_bounds__(256)
void scan_a_kernel(const int* __restrict__ deg, int* __restrict__ partials)
{
    __shared__ int ls[256];
    int b = blockIdx.x, t = threadIdx.x;
    int s = 0;
    for (int j = 0; j < 4; ++j) {
        int i = b * 1024 + t * 4 + j;
        if (i < N_NODES) s += deg[i];
    }
    ls[t] = s; __syncthreads();
    for (int o = 128; o > 0; o >>= 1) {
        if (t < o) ls[t] += ls[t + o];
        __syncthreads();
    }
    if (t == 0) partials[b] = ls[0];
}

__global__ void scan_b_kernel(const int* __restrict__ partials, int* __restrict__ pofs)
{
    if (threadIdx.x == 0) {
        int a = 0;
        for (int i = 0; i < SCAN_B; ++i) { pofs[i] = a; a += partials[i]; }
    }
}

__global__ __launch_bounds__(256)
void scan_c_kernel(const int* __restrict__ deg, const int* __restrict__ pofs,
                   int* __restrict__ row_ptr, int* __restrict__ cursor)
{
    __shared__ int ls[256];
    int b = blockIdx.x, t = threadIdx.x;
    int v[4], s = 0;
    for (int j = 0; j < 4; ++j) {
        int i = b * 1024 + t * 4 + j;
        v[j] = (i < N_NODES) ? deg[i] : 0;
        s += v[j];
    }
    ls[t] = s; __syncthreads();
    for (int o = 1; o < 256; o <<= 1) {
        int tv = (t >= o) ? ls[t - o] : 0;
        __syncthreads();
        ls[t] += tv;
        __syncthreads();
    }
    int excl = ls[t] - s + pofs[b];
    for (int j = 0; j < 4; ++j) {
        int i = b * 1024 + t * 4 + j;
        if (i < N_NODES) { row_ptr[i] = excl; cursor[i] = excl; excl += v[j]; }
    }
    if (b == 0 && t == 0) row_ptr[N_NODES] = N_EDGES;
}

__global__ __launch_bounds__(256)
void scatter_kernel(const int* __restrict__ src, const int* __restrict__ dst,
                    int* __restrict__ cursor, int* __restrict__ csr_src)
{
    int i = blockIdx.x * 256 + threadIdx.x;
    if (i < N_EDGES) {
        int p = atomicAdd(&cursor[dst[i]], 1);
        csr_src[p] = src[i];
    }
}

// ---------------------------------------------------------------------------
// mean + max aggregation. 16 lanes per node, 16B loads per lane per edge.
__global__ __launch_bounds__(256)
void agg_kernel(const bf16_t* __restrict__ h, const int* __restrict__ row_ptr,
                const int* __restrict__ csr_src,
                bf16_t* __restrict__ mean_o, bf16_t* __restrict__ max_o)
{
    int node = blockIdx.x * 16 + (threadIdx.x >> 4);   // grid exact: N/16
    int dd = (threadIdx.x & 15) * 8;
    int e0 = row_ptr[node], e1 = row_ptr[node + 1];
    float s[8], mx[8];
#pragma unroll
    for (int j = 0; j < 8; ++j) { s[j] = 0.f; mx[j] = 0.f; }
    for (int e = e0; e < e1; ++e) {
        int sc = csr_src[e];
        bf16x8 v = *(const bf16x8*)&h[(long)sc * 128 + dd];
#pragma unroll
        for (int j = 0; j < 8; ++j) {
            float f = (float)v[j];
            s[j] += f;
            mx[j] = fmaxf(mx[j], f);
        }
    }
    float inv = 1.f / fmaxf((float)(e1 - e0), 1.f);
    bf16x8 om, ox;
#pragma unroll
    for (int j = 0; j < 8; ++j) { om[j] = (bf16_t)(s[j] * inv); ox[j] = (bf16_t)mx[j]; }
    *(bf16x8*)&mean_o[(long)node * 128 + dd] = om;
    *(bf16x8*)&max_o [(long)node * 128 + dd] = ox;
}

// ---------------------------------------------------------------------------
// async global->LDS, 16B per lane. LDS dest must be wave-uniform base + lane*16.
__device__ __forceinline__ void gload_lds16(const bf16_t* g, bf16_t* l)
{
    __builtin_amdgcn_global_load_lds(
        (const __attribute__((address_space(1))) void*)g,
        (__attribute__((address_space(3))) void*)l, 16, 0, 0);
}

// lgkm-only barrier: orders LDS writes->reads across waves WITHOUT draining
// vmcnt — keeps any in-flight prefetch DMA alive through the epilogue.
__device__ __forceinline__ void barrier_lgkm()
{
    asm volatile("s_waitcnt lgkmcnt(0)" ::: "memory");
    __builtin_amdgcn_s_barrier();
    asm volatile("" ::: "memory");
}

// device-wide barrier. SAFETY: callers use LDS > 80 KB => 1 block/CU, and
// grid == 256 == #CUs => all blocks co-resident by construction. Counter is
// pre-zeroed per launch; a stale counter (rocprof single-dispatch replay)
// only falls through, never deadlocks.
__device__ __forceinline__ void grid_bar(int* c)
{
    __syncthreads();
    if (threadIdx.x == 0) {
        __threadfence();   // release: flush this XCD's L2 (plain stores visible)
        __hip_atomic_fetch_add(c, 1, __ATOMIC_ACQ_REL, __HIP_MEMORY_SCOPE_AGENT);
        while (__hip_atomic_load(c, __ATOMIC_ACQUIRE, __HIP_MEMORY_SCOPE_AGENT) < GRIDG)
            __builtin_amdgcn_s_sleep(2);
        __threadfence();   // acquire: invalidate caches before reading others' data
    }
    __syncthreads();
    __threadfence();
}

// ---------------------------------------------------------------------------
// Fused mixed-op kernel: replaces gemm + reduce_stats + passc (+ final for
// mode 1) in ONE persistent dispatch, eliminating the 77 MB y write and the
// 77 MB y read-back (R2 showed this traffic runs at only ~2.2 TB/s).
//   Phase A: per (tile,c) item: stage W_c + x_c, MFMA, epilogue computes
//            per-feature (sum,sumsq) partials ONLY (y is discarded).
//   grid_bar -> 48-block fold of partials -> grid_bar -> every block builds
//            per-feature affine coefs A,B in LDS (bias/mu/rsqrt/g/be and the
//            k-mix weight folded; w_k>=0 so w*relu(v)=relu(w*v)).
//   Phase B: tile-major recompute of each y_c tile (x now L3-hot), emitting
//            state = sum_c relu(A_c*acc+B_c) directly as bf16 (mode 0), or
//            the final fp32 relu-normalized output (mode 1, K=384 cat GEMM).
// mode 0: c = k (3 independent GEMMs, res accumulated across c).
// mode 1: c = K-chunk (acc carried across c), epilogue at c==2.
__global__ __launch_bounds__(512, 1)
void mixed_kernel(const bf16_t* __restrict__ x0, const bf16_t* __restrict__ x1,
                  const bf16_t* __restrict__ x2, const bf16_t* __restrict__ wt,
                  const float* __restrict__ bias, const float* __restrict__ gg,
                  const float* __restrict__ be, const float* __restrict__ wmix,
                  bf16_t* __restrict__ outb, float* __restrict__ outf,
                  float* __restrict__ partial, float* __restrict__ tmp,
                  int* __restrict__ cnt, int mode, int accflag)
{
    __shared__ __align__(16) bf16_t lds_w[2][16384];   // W slots (2 x 32 KB)
    __shared__ __align__(16) bf16_t lds_x[2][16384];   // x slots (2 x 32 KB)
    __shared__ float lsc[768];                         // lred (A) / coefs (B)

    const int tid  = threadIdx.x;
    const int lane = tid & 63;
    const int w8   = tid >> 6;
    const int quad = lane >> 4;
    const int t16  = lane & 15;
    const int wr = w8 >> 2, wc = w8 & 3;
    const int bid = blockIdx.x;
    const float invN = 1.0f / (float)N_NODES;

    // staging offsets: linear LDS dest, XOR swizzle in the global source
    int srcoff[4], dsto[4];
#pragma unroll
    for (int i = 0; i < 4; ++i) {
        int ci = i * 512 + tid;
        int row = ci >> 4, c = ci & 15;
        srcoff[i] = row * 128 + ((c ^ (row & 15)) * 8);
        dsto[i]   = ci * 8;
    }
    auto stage = [&](const bf16_t* src, bf16_t* dst) {
#pragma unroll
        for (int i = 0; i < 4; ++i)
            gload_lds16(src + srcoff[i], dst + dsto[i]);
    };
    auto xp = [&](int c) { return (c == 0) ? x0 : (c == 1) ? x1 : x2; };

    const int ts = (int)(((long)bid * NTILES) / GRIDG);
    const int te = (int)(((long)(bid + 1) * NTILES) / GRIDG);
    const int w0 = ts * 3, w1 = te * 3;
    const int nk = (mode == 0) ? 3 : 1;

    f32x4 acc[2][4];

    // ---------------- Phase A: stats only ----------------
    {
        int tile = ts, c = 0, p = 0;
        stage(wt, lds_w[0]);
        stage(x0 + (long)ts * 16384, lds_x[0]);
        for (int w = w0; w < w1; ++w) {
            __syncthreads();                      // drain DMA for item w
            int cn = c + 1, tn = tile;
            if (cn == 3) { cn = 0; tn = tile + 1; }
            if (w + 1 < w1) {
                stage(wt + (long)cn * 16384, lds_w[p ^ 1]);
                stage(xp(cn) + (long)tn * 16384, lds_x[p ^ 1]);
            }
            if (mode == 0 || c == 0) {
#pragma unroll
                for (int a = 0; a < 2; ++a)
#pragma unroll
                    for (int b = 0; b < 4; ++b) acc[a][b] = (f32x4){0.f, 0.f, 0.f, 0.f};
            }
#pragma unroll
            for (int ks = 0; ks < 4; ++ks) {
                bf16x8 xf[4], wf[2];
#pragma unroll
                for (int ms = 0; ms < 4; ++ms) {
                    int row = wr * 64 + ms * 16 + t16;
                    int sw = (ks * 4 + quad) ^ t16;
                    xf[ms] = *(const bf16x8*)&lds_x[p][row * 128 + sw * 8];
                }
#pragma unroll
                for (int ns = 0; ns < 2; ++ns) {
                    int row = wc * 32 + ns * 16 + t16;
                    int sw = (ks * 4 + quad) ^ t16;
                    wf[ns] = *(const bf16x8*)&lds_w[p][row * 128 + sw * 8];
                }
#pragma unroll
                for (int ns = 0; ns < 2; ++ns)
#pragma unroll
                    for (int ms = 0; ms < 4; ++ms)
                        acc[ns][ms] = __builtin_amdgcn_mfma_f32_16x16x32_bf16(
                            wf[ns], xf[ms], acc[ns][ms], 0, 0, 0);
            }
            if (mode == 0 || c == 2) {
                const float* bp = bias + ((mode == 0) ? c * 128 : 0);
                float ss[8], sq[8];
#pragma unroll
                for (int i = 0; i < 8; ++i) { ss[i] = 0.f; sq[i] = 0.f; }
#pragma unroll
                for (int ms = 0; ms < 4; ++ms) {
                    long m = (long)tile * 128 + wr * 64 + ms * 16 + t16;
                    if (m < N_NODES) {
#pragma unroll
                        for (int ns = 0; ns < 2; ++ns) {
                            int n0 = wc * 32 + ns * 16 + quad * 4;
                            float4 b4 = *(const float4*)&bp[n0];
                            float v0 = acc[ns][ms][0] + b4.x;
                            float v1 = acc[ns][ms][1] + b4.y;
                            float v2 = acc[ns][ms][2] + b4.z;
                            float v3 = acc[ns][ms][3] + b4.w;
                            ss[ns * 4 + 0] += v0; sq[ns * 4 + 0] += v0 * v0;
                            ss[ns * 4 + 1] += v1; sq[ns * 4 + 1] += v1 * v1;
                            ss[ns * 4 + 2] += v2; sq[ns * 4 + 2] += v2 * v2;
                            ss[ns * 4 + 3] += v3; sq[ns * 4 + 3] += v3 * v3;
                        }
                    }
                }
#pragma unroll
                for (int o = 1; o < 16; o <<= 1) {
#pragma unroll
                    for (int i = 0; i < 8; ++i) {
                        ss[i] += __shfl_xor(ss[i], o);
                        sq[i] += __shfl_xor(sq[i], o);
                    }
                }
                if (t16 == 0) {
#pragma unroll
                    for (int ns = 0; ns < 2; ++ns)
#pragma unroll
                        for (int i = 0; i < 4; ++i) {
                            lsc[w8 * 64 +      ns * 16 + quad * 4 + i] = ss[ns * 4 + i];
                            lsc[w8 * 64 + 32 + ns * 16 + quad * 4 + i] = sq[ns * 4 + i];
                        }
                }
                barrier_lgkm();
                if (tid < 256) {
                    int selo = (tid >> 7) * 32;
                    int d = tid & 127;
                    int wcq = d >> 5, f = d & 31;
                    float v = lsc[wcq * 64 + selo + f] + lsc[(wcq + 4) * 64 + selo + f];
                    int slice = (mode == 0) ? c : 0;
                    partial[((long)slice * NTILES + tile) * 256 + tid] = v;
                }
            }
            p ^= 1; c = cn; tile = tn;
        }
    }

    // ---------------- stats fold + coefficients ----------------
    grid_bar(cnt + 0);
    if (bid < nk * 16 && tid < 256) {          // level-1 fold: 49 tiles/block
        int k = bid >> 4, j = bid & 15;
        int b0 = j * 49, b1 = (b0 + 49 < NTILES) ? b0 + 49 : NTILES;
        float s = 0.f;
        const float* pp = partial + (long)k * NTILES * 256 + tid;
        for (int b = b0; b < b1; ++b) s += pp[(long)b * 256];
        tmp[(k * 16 + j) * 256 + tid] = s;
    }
    grid_bar(cnt + 1);
    if (tid < 128) {                           // per-block coef build
        for (int k = 0; k < nk; ++k) {
            float S = 0.f, Q = 0.f;
#pragma unroll
            for (int j = 0; j < 16; ++j) {
                S += tmp[(k * 16 + j) * 256 + tid];
                Q += tmp[(k * 16 + j) * 256 + 128 + tid];
            }
            float mu = S * invN;
            float var = Q * invN - mu * mu;
            float rs = rsqrtf(var + EPS_F);
            float gk = gg[k * 128 + tid], bek = be[k * 128 + tid];
            float bk = bias[k * 128 + tid];
            float wk = (mode == 0) ? wmix[k] : 1.f;
            lsc[k * 256 + tid]       = wk * rs * gk;
            lsc[k * 256 + 128 + tid] = wk * ((bk - mu) * rs * gk + bek);
        }
    }
    __syncthreads();

    // ---------------- Phase B: recompute + emit ----------------
    {
        int tile = ts, c = 0, p = 0;
        f32x4 res[2][4];
        stage(wt, lds_w[0]);
        stage(x0 + (long)ts * 16384, lds_x[0]);
        for (int w = w0; w < w1; ++w) {
            __syncthreads();
            int cn = c + 1, tn = tile;
            if (cn == 3) { cn = 0; tn = tile + 1; }
            if (w + 1 < w1) {
                stage(wt + (long)cn * 16384, lds_w[p ^ 1]);
                stage(xp(cn) + (long)tn * 16384, lds_x[p ^ 1]);
            }
            if (mode == 0 || c == 0) {
#pragma unroll
                for (int a = 0; a < 2; ++a)
#pragma unroll
                    for (int b = 0; b < 4; ++b) acc[a][b] = (f32x4){0.f, 0.f, 0.f, 0.f};
            }
            if (mode == 0 && c == 0) {
                if (accflag) {
#pragma unroll
                    for (int ns = 0; ns < 2; ++ns)
#pragma unroll
                        for (int ms = 0; ms < 4; ++ms) {
                            long m = (long)tile * 128 + wr * 64 + ms * 16 + t16;
                            int n0 = wc * 32 + ns * 16 + quad * 4;
                            bf16x4 pv = *(const bf16x4*)&outb[m * 128 + n0];
                            res[ns][ms] = (f32x4){(float)pv[0], (float)pv[1],
                                                  (float)pv[2], (float)pv[3]};
                        }
                } else {
#pragma unroll
                    for (int a = 0; a < 2; ++a)
#pragma unroll
                        for (int b = 0; b < 4; ++b) res[a][b] = (f32x4){0.f, 0.f, 0.f, 0.f};
                }
            }
#pragma unroll
            for (int ks = 0; ks < 4; ++ks) {
                bf16x8 xf[4], wf[2];
#pragma unroll
                for (int ms = 0; ms < 4; ++ms) {
                    int row = wr * 64 + ms * 16 + t16;
                    int sw = (ks * 4 + quad) ^ t16;
                    xf[ms] = *(const bf16x8*)&lds_x[p][row * 128 + sw * 8];
                }
#pragma unroll
                for (int ns = 0; ns < 2; ++ns) {
                    int row = wc * 32 + ns * 16 + t16;
                    int sw = (ks * 4 + quad) ^ t16;
                    wf[ns] = *(const bf16x8*)&lds_w[p][row * 128 + sw * 8];
                }
#pragma unroll
                for (int ns = 0; ns < 2; ++ns)
#pragma unroll
                    for (int ms = 0; ms < 4; ++ms)
                        acc[ns][ms] = __builtin_amdgcn_mfma_f32_16x16x32_bf16(
                            wf[ns], xf[ms], acc[ns][ms], 0, 0, 0);
            }
            if (mode == 0) {
#pragma unroll
                for (int ns = 0; ns < 2; ++ns) {
                    int n0 = wc * 32 + ns * 16 + quad * 4;
                    float4 A4 = *(const float4*)&lsc[c * 256 + n0];
                    float4 B4 = *(const float4*)&lsc[c * 256 + 128 + n0];
#pragma unroll
                    for (int ms = 0; ms < 4; ++ms) {
                        res[ns][ms][0] += fmaxf(acc[ns][ms][0] * A4.x + B4.x, 0.f);
                        res[ns][ms][1] += fmaxf(acc[ns][ms][1] * A4.y + B4.y, 0.f);
                        res[ns][ms][2] += fmaxf(acc[ns][ms][2] * A4.z + B4.z, 0.f);
                        res[ns][ms][3] += fmaxf(acc[ns][ms][3] * A4.w + B4.w, 0.f);
                    }
                }
                if (c == 2) {
#pragma unroll
                    for (int ms = 0; ms < 4; ++ms) {
                        long m = (long)tile * 128 + wr * 64 + ms * 16 + t16;
                        if (m < N_NODES) {
#pragma unroll
                            for (int ns = 0; ns < 2; ++ns) {
                                int n0 = wc * 32 + ns * 16 + quad * 4;
                                bf16x4 ov;
                                ov[0] = (bf16_t)res[ns][ms][0];
                                ov[1] = (bf16_t)res[ns][ms][1];
                                ov[2] = (bf16_t)res[ns][ms][2];
                                ov[3] = (bf16_t)res[ns][ms][3];
                                *(bf16x4*)&outb[m * 128 + n0] = ov;
                            }
                        }
                    }
                }
            } else if (c == 2) {
#pragma unroll
                for (int ms = 0; ms < 4; ++ms) {
                    long m = (long)tile * 128 + wr * 64 + ms * 16 + t16;
                    if (m < N_NODES) {
#pragma unroll
                        for (int ns = 0; ns < 2; ++ns) {
                            int n0 = wc * 32 + ns * 16 + quad * 4;
                            float4 A4 = *(const float4*)&lsc[n0];
                            float4 B4 = *(const float4*)&lsc[128 + n0];
                            float4 o;
                            o.x = fmaxf(acc[ns][ms][0] * A4.x + B4.x, 0.f);
                            o.y = fmaxf(acc[ns][ms][1] * A4.y + B4.y, 0.f);
                            o.z = fmaxf(acc[ns][ms][2] * A4.z + B4.z, 0.f);
                            o.w = fmaxf(acc[ns][ms][3] * A4.w + B4.w, 0.f);
                            *(float4*)&outf[m * 128 + n0] = o;
                        }
                    }
                }
            }
            p ^= 1; c = cn; tile = tn;
        }
    }
}

// ---------------------------------------------------------------------------
extern "C" void kernel_launch(void* const* d_in, const int* in_sizes, int n_in,
                              void* d_out, int out_size, void* d_ws, size_t ws_size,
                              hipStream_t stream)
{
    const float* src_emb = (const float*)d_in[0];
    const float* hr      = (const float*)d_in[1];
    const int*   e_src   = (const int*)d_in[2];
    const int*   e_dst   = (const int*)d_in[3];
    const float* w_zero  = (const float*)d_in[4];
    const float* w_first = (const float*)d_in[5];
    const float* w_mid   = (const float*)d_in[6];
    const float* w_last  = (const float*)d_in[7];
    const float* W_zero  = (const float*)d_in[8];
    const float* b_zero  = (const float*)d_in[9];
    const float* g_zero  = (const float*)d_in[10];
    const float* be_zero = (const float*)d_in[11];
    const float* W_first = (const float*)d_in[12];
    const float* b_first = (const float*)d_in[13];
    const float* g_first = (const float*)d_in[14];
    const float* be_first= (const float*)d_in[15];
    const float* W_mid   = (const float*)d_in[16];
    const float* b_mid   = (const float*)d_in[17];
    const float* g_mid   = (const float*)d_in[18];
    const float* be_mid  = (const float*)d_in[19];
    const float* W_last  = (const float*)d_in[20];
    const float* b_last  = (const float*)d_in[21];
    const float* g_last  = (const float*)d_in[22];
    const float* be_last = (const float*)d_in[23];
    const float* W_cat   = (const float*)d_in[24];
    const float* b_cat   = (const float*)d_in[25];
    const float* g_cat   = (const float*)d_in[26];
    const float* be_cat  = (const float*)d_in[27];
    float* out = (float*)d_out;

    char* ws = (char*)d_ws;
    size_t off = 0;
    auto carve = [&](size_t bytes) -> char* {
        off = (off + 255) & ~(size_t)255;
        char* p = ws + off;
        off += bytes;
        return p;
    };

    const size_t SB = (size_t)NPAD * 128 * sizeof(bf16_t);
    bf16_t* B[8];
    for (int i = 0; i < 8; ++i) B[i] = (bf16_t*)carve(SB);
    bf16_t* wt    = (bf16_t*)carve((size_t)27 * 16384 * 2);
    float*  partial = (float*)carve((size_t)3 * NTILES * 256 * sizeof(float));
    float*  tmp   = (float*)carve((size_t)48 * 256 * sizeof(float));
    int* cnts   = (int*)carve(32 * 4);
    int* deg    = (int*)carve((size_t)N_NODES * 4);
    int* rowp   = (int*)carve((size_t)(N_NODES + 1) * 4);
    int* cursor = (int*)carve((size_t)N_NODES * 4);
    int* csr    = (int*)carve((size_t)N_EDGES * 4);
    int* parts  = (int*)carve(SCAN_B * 4);
    int* pofs   = (int*)carve(SCAN_B * 4);

    bf16_t* wtZ  = wt;
    bf16_t* wtF0 = wt + (size_t)3  * 16384;
    bf16_t* wtF1 = wt + (size_t)6  * 16384;
    bf16_t* wtF2 = wt + (size_t)9  * 16384;
    bf16_t* wtM0 = wt + (size_t)12 * 16384;
    bf16_t* wtM1 = wt + (size_t)15 * 16384;
    bf16_t* wtL0 = wt + (size_t)18 * 16384;
    bf16_t* wtL1 = wt + (size_t)21 * 16384;
    bf16_t* wtC  = wt + (size_t)24 * 16384;

    const int GEL8 = (N_NODES * 128) / 2048;   // 6250, exact

    init_zero_kernel<<<dim3((N_NODES + 255) / 256), dim3(256), 0, stream>>>(deg, cnts);
    transpose_w_kernel<<<dim3(1728), dim3(256), 0, stream>>>(W_zero, W_first, W_mid, W_last, W_cat, wt);
    deg_count_kernel<<<dim3((N_EDGES + 255) / 256), dim3(256), 0, stream>>>(e_dst, deg);
    scan_a_kernel<<<dim3(SCAN_B), dim3(256), 0, stream>>>(deg, parts);
    scan_b_kernel<<<dim3(1), dim3(64), 0, stream>>>(parts, pofs);
    scan_c_kernel<<<dim3(SCAN_B), dim3(256), 0, stream>>>(deg, pofs, rowp, cursor);
    scatter_kernel<<<dim3((N_EDGES + 255) / 256), dim3(256), 0, stream>>>(e_src, e_dst, cursor, csr);

    auto M = [&](const bf16_t* x0_, const bf16_t* x1_, const bf16_t* x2_,
                 const bf16_t* w_, const float* b_, const float* g_, const float* be_,
                 const float* wm_, bf16_t* ob_, float* of_, int acc_, int mode_, int id) {
        mixed_kernel<<<dim3(GRIDG), dim3(512), 0, stream>>>(
            x0_, x1_, x2_, w_, b_, g_, be_, wm_, ob_, of_,
            partial, tmp, cnts + id * 2, mode_, acc_);
    };
    auto A = [&](const bf16_t* h_, bf16_t* me_, bf16_t* mx_) {
        agg_kernel<<<dim3(N_NODES / 16), dim3(256), 0, stream>>>(h_, rowp, csr, me_, mx_);
    };

    // zero op: pre -> B3,B4,B5 ; h_in = B6
    pre_kernel<<<dim3(GEL8), dim3(256), 0, stream>>>(src_emb, hr, B[3], B[4], B[5]);
    M(B[3], B[4], B[5], wtZ, b_zero, g_zero, be_zero, w_zero, B[6], nullptr, 0, 0, 0);

    A(B[6], B[3], B[4]);                                             // aggH -> B3,B4

    // s0 = mixed([h_in, aggH], first0)                              // s0 = B5
    M(B[6], B[3], B[4], wtF0, b_first + 0, g_first + 0, be_first + 0,
      w_first + 0, B[5], nullptr, 0, 0, 1);
    // s1 (h_in contribution first)                                  // s1 = B7
    M(B[6], B[3], B[4], wtF1, b_first + 384, g_first + 384, be_first + 384,
      w_first + 3, B[7], nullptr, 0, 0, 2);
    // h_in(B6), aggH(B3,B4) dead

    A(B[5], B[3], B[4]);                                             // aggS0 -> B3,B4

    // s1 += mixed([s0, aggS0], first2)
    M(B[5], B[3], B[4], wtF2, b_first + 768, g_first + 768, be_first + 768,
      w_first + 6, B[7], nullptr, 1, 0, 3);
    // m0 = mixed([s0, aggS0], mid0)                                 // m0 = B6
    M(B[5], B[3], B[4], wtM0, b_mid + 0, g_mid + 0, be_mid + 0,
      w_mid + 0, B[6], nullptr, 0, 0, 4);
    // s0(B5), aggS0(B3,B4) dead

    A(B[7], B[3], B[4]);                                             // aggS1 -> B3,B4

    // m1 = mixed([s1, aggS1], mid1)                                 // m1 = B5
    M(B[7], B[3], B[4], wtM1, b_mid + 384, g_mid + 384, be_mid + 384,
      w_mid + 3, B[5], nullptr, 0, 0, 5);
    // s1(B7), aggS1(B3,B4) dead

    // s_last = mixed([m0, agg m0], last0) + mixed([m1, agg m1], last1)  // sl = B7
    A(B[6], B[3], B[4]);
    M(B[6], B[3], B[4], wtL0, b_last + 0, g_last + 0, be_last + 0,
      w_last + 0, B[7], nullptr, 0, 0, 6);
    A(B[5], B[3], B[4]);
    M(B[5], B[3], B[4], wtL1, b_last + 384, g_last + 384, be_last + 384,
      w_last + 3, B[7], nullptr, 1, 0, 7);

    // out = relu(norm([m0 | m1 | s_last] @ W_cat + b_cat)) directly to fp32
    M(B[6], B[5], B[7], wtC, b_cat, g_cat, be_cat, nullptr,
      nullptr, out, 0, 1, 8);
}

// Round 4
// 1283.972 us; speedup vs baseline: 2.0104x; 2.0104x over previous
//
#include <hip/hip_runtime.h>

#define N_NODES 100000
#define N_EDGES 600000
#define NPAD    100096      // 782 * 128
#define NTILES  782
#define SCAN_B  98          // ceil(100000/1024)
#define EPS_F   1e-5f
#define GRIDG   256         // persistent mixed grid: 1 block (8 waves) per CU

typedef __bf16 bf16_t;
typedef __bf16 bf16x8 __attribute__((ext_vector_type(8)));
typedef __bf16 bf16x4 __attribute__((ext_vector_type(4)));
typedef float  f32x4  __attribute__((ext_vector_type(4)));

// ---------------------------------------------------------------------------
// zero deg + grid-barrier counters
__global__ __launch_bounds__(256)
void init_zero_kernel(int* __restrict__ deg, int* __restrict__ cnt)
{
    int i = blockIdx.x * 256 + threadIdx.x;
    if (i < N_NODES) deg[i] = 0;
    if (i < 32) cnt[i] = 0;
}

// ---------------------------------------------------------------------------
// Weight pre-transpose: WT[mat][n][k] = W[mat][k][n], fp32 -> bf16.
__global__ __launch_bounds__(256)
void transpose_w_kernel(const float* __restrict__ Wz, const float* __restrict__ Wf,
                        const float* __restrict__ Wm, const float* __restrict__ Wl,
                        const float* __restrict__ Wc, bf16_t* __restrict__ wt)
{
    int idx = blockIdx.x * 256 + threadIdx.x;      // < 27*16384, exact grid
    int mat = idx >> 14;
    int off = idx & 16383;
    int n = off >> 7, kk = off & 127;
    const float* src;
    if      (mat < 3)  src = Wz + mat * 16384;
    else if (mat < 12) src = Wf + (mat - 3) * 16384;
    else if (mat < 18) src = Wm + (mat - 12) * 16384;
    else if (mat < 24) src = Wl + (mat - 18) * 16384;
    else               src = Wc + (mat - 24) * 16384;
    wt[idx] = (bf16_t)src[kk * 128 + n];
}

// ---------------------------------------------------------------------------
// pre-candidates, vectorized 8 elems/thread: [se, se-hr, se*hr] as bf16
__global__ __launch_bounds__(256)
void pre_kernel(const float* __restrict__ se, const float* __restrict__ hr,
                bf16_t* __restrict__ p0, bf16_t* __restrict__ p1, bf16_t* __restrict__ p2)
{
    long i = ((long)blockIdx.x * 256 + threadIdx.x) * 8;   // grid exact: N*128/2048
    float4 a0 = *(const float4*)&se[i], a1 = *(const float4*)&se[i + 4];
    float4 b0 = *(const float4*)&hr[i], b1 = *(const float4*)&hr[i + 4];
    float av[8] = {a0.x, a0.y, a0.z, a0.w, a1.x, a1.y, a1.z, a1.w};
    float bv[8] = {b0.x, b0.y, b0.z, b0.w, b1.x, b1.y, b1.z, b1.w};
    bf16x8 o0, o1, o2;
#pragma unroll
    for (int j = 0; j < 8; ++j) {
        o0[j] = (bf16_t)av[j];
        o1[j] = (bf16_t)(av[j] - bv[j]);
        o2[j] = (bf16_t)(av[j] * bv[j]);
    }
    *(bf16x8*)&p0[i] = o0;
    *(bf16x8*)&p1[i] = o1;
    *(bf16x8*)&p2[i] = o2;
}

// ---------------------------------------------------------------------------
// CSR build
__global__ __launch_bounds__(256)
void deg_count_kernel(const int* __restrict__ dst, int* __restrict__ deg)
{
    int i = blockIdx.x * 256 + threadIdx.x;
    if (i < N_EDGES) atomicAdd(&deg[dst[i]], 1);
}

__global__ __launch_bounds__(256)
void scan_a_kernel(const int* __restrict__ deg, int* __restrict__ partials)
{
    __shared__ int ls[256];
    int b = blockIdx.x, t = threadIdx.x;
    int s = 0;
    for (int j = 0; j < 4; ++j) {
        int i = b * 1024 + t * 4 + j;
        if (i < N_NODES) s += deg[i];
    }
    ls[t] = s; __syncthreads();
    for (int o = 128; o > 0; o >>= 1) {
        if (t < o) ls[t] += ls[t + o];
        __syncthreads();
    }
    if (t == 0) partials[b] = ls[0];
}

__global__ void scan_b_kernel(const int* __restrict__ partials, int* __restrict__ pofs)
{
    if (threadIdx.x == 0) {
        int a = 0;
        for (int i = 0; i < SCAN_B; ++i) { pofs[i] = a; a += partials[i]; }
    }
}

__global__ __launch_bounds__(256)
void scan_c_kernel(const int* __restrict__ deg, const int* __restrict__ pofs,
                   int* __restrict__ row_ptr, int* __restrict__ cursor)
{
    __shared__ int ls[256];
    int b = blockIdx.x, t = threadIdx.x;
    int v[4], s = 0;
    for (int j = 0; j < 4; ++j) {
        int i = b * 1024 + t * 4 + j;
        v[j] = (i < N_NODES) ? deg[i] : 0;
        s += v[j];
    }
    ls[t] = s; __syncthreads();
    for (int o = 1; o < 256; o <<= 1) {
        int tv = (t >= o) ? ls[t - o] : 0;
        __syncthreads();
        ls[t] += tv;
        __syncthreads();
    }
    int excl = ls[t] - s + pofs[b];
    for (int j = 0; j < 4; ++j) {
        int i = b * 1024 + t * 4 + j;
        if (i < N_NODES) { row_ptr[i] = excl; cursor[i] = excl; excl += v[j]; }
    }
    if (b == 0 && t == 0) row_ptr[N_NODES] = N_EDGES;
}

__global__ __launch_bounds__(256)
void scatter_kernel(const int* __restrict__ src, const int* __restrict__ dst,
                    int* __restrict__ cursor, int* __restrict__ csr_src)
{
    int i = blockIdx.x * 256 + threadIdx.x;
    if (i < N_EDGES) {
        int p = atomicAdd(&cursor[dst[i]], 1);
        csr_src[p] = src[i];
    }
}

// ---------------------------------------------------------------------------
// mean + max aggregation. 16 lanes per node, 16B loads per lane per edge.
__global__ __launch_bounds__(256)
void agg_kernel(const bf16_t* __restrict__ h, const int* __restrict__ row_ptr,
                const int* __restrict__ csr_src,
                bf16_t* __restrict__ mean_o, bf16_t* __restrict__ max_o)
{
    int node = blockIdx.x * 16 + (threadIdx.x >> 4);   // grid exact: N/16
    int dd = (threadIdx.x & 15) * 8;
    int e0 = row_ptr[node], e1 = row_ptr[node + 1];
    float s[8], mx[8];
#pragma unroll
    for (int j = 0; j < 8; ++j) { s[j] = 0.f; mx[j] = 0.f; }
    for (int e = e0; e < e1; ++e) {
        int sc = csr_src[e];
        bf16x8 v = *(const bf16x8*)&h[(long)sc * 128 + dd];
#pragma unroll
        for (int j = 0; j < 8; ++j) {
            float f = (float)v[j];
            s[j] += f;
            mx[j] = fmaxf(mx[j], f);
        }
    }
    float inv = 1.f / fmaxf((float)(e1 - e0), 1.f);
    bf16x8 om, ox;
#pragma unroll
    for (int j = 0; j < 8; ++j) { om[j] = (bf16_t)(s[j] * inv); ox[j] = (bf16_t)mx[j]; }
    *(bf16x8*)&mean_o[(long)node * 128 + dd] = om;
    *(bf16x8*)&max_o [(long)node * 128 + dd] = ox;
}

// ---------------------------------------------------------------------------
// async global->LDS, 16B per lane. LDS dest must be wave-uniform base + lane*16.
__device__ __forceinline__ void gload_lds16(const bf16_t* g, bf16_t* l)
{
    __builtin_amdgcn_global_load_lds(
        (const __attribute__((address_space(1))) void*)g,
        (__attribute__((address_space(3))) void*)l, 16, 0, 0);
}

// lgkm-only barrier: orders LDS writes->reads across waves WITHOUT draining
// vmcnt — keeps any in-flight prefetch DMA alive through the epilogue.
__device__ __forceinline__ void barrier_lgkm()
{
    asm volatile("s_waitcnt lgkmcnt(0)" ::: "memory");
    __builtin_amdgcn_s_barrier();
    asm volatile("" ::: "memory");
}

// device-wide barrier. SAFETY: callers use LDS > 80 KB => 1 block/CU, and
// grid == 256 == #CUs => all blocks co-resident by construction. Counter is
// pre-zeroed per launch; stale counters (rocprof single-dispatch replay)
// only fall through, never deadlock.
// R3 lesson: the spin must use RELAXED loads — an ACQUIRE agent-scope load
// emits a full L2 invalidate PER SPIN ITERATION (cache-maintenance storm,
// 5x slowdown). Here: one release fence before arrival, relaxed spin, one
// acquire fence on exit — and only where that block produces/consumes.
__device__ __forceinline__ void grid_bar(int* c, int do_rel, int do_acq)
{
    __syncthreads();                       // all waves' stores complete-to-L2
    if (threadIdx.x == 0) {
        if (do_rel) __builtin_amdgcn_fence(__ATOMIC_RELEASE, "agent");  // wbl2
        __hip_atomic_fetch_add(c, 1, __ATOMIC_RELAXED, __HIP_MEMORY_SCOPE_AGENT);
        while (__hip_atomic_load(c, __ATOMIC_RELAXED, __HIP_MEMORY_SCOPE_AGENT) < GRIDG)
            __builtin_amdgcn_s_sleep(16);
        if (do_acq) __builtin_amdgcn_fence(__ATOMIC_ACQUIRE, "agent");  // inv
    }
    __syncthreads();
}

// ---------------------------------------------------------------------------
// Fused mixed-op kernel: gemm + stats + normalize-affine-relu-mix in ONE
// persistent dispatch; y is never materialized (recomputed in phase B).
//   Phase A (mode 0: k-major like R2's proven gemm; mode 1: c-fastest):
//     stage W/x, MFMA, per-feature (sum,sumsq) partials only.
//   grid_bar -> 48-block fold -> grid_bar -> per-block coef build (A,B).
//   Phase B (tile-major, c fastest): recompute acc per (tile,c), emit
//     state = sum_c relu(A_c*acc+B_c) as bf16 (mode 0) or final fp32 (mode 1).
__global__ __launch_bounds__(512, 1)
void mixed_kernel(const bf16_t* __restrict__ x0, const bf16_t* __restrict__ x1,
                  const bf16_t* __restrict__ x2, const bf16_t* __restrict__ wt,
                  const float* __restrict__ bias, const float* __restrict__ gg,
                  const float* __restrict__ be, const float* __restrict__ wmix,
                  bf16_t* __restrict__ outb, float* __restrict__ outf,
                  float* __restrict__ partial, float* __restrict__ tmp,
                  int* __restrict__ cnt, int mode, int accflag)
{
    __shared__ __align__(16) bf16_t lds_w[2][16384];   // W slots (2 x 32 KB)
    __shared__ __align__(16) bf16_t lds_x[2][16384];   // x slots (2 x 32 KB)
    __shared__ float lsc[768];                         // lred (A) / coefs (B)

    const int tid  = threadIdx.x;
    const int lane = tid & 63;
    const int w8   = tid >> 6;
    const int quad = lane >> 4;
    const int t16  = lane & 15;
    const int wr = w8 >> 2, wc = w8 & 3;
    const int bid = blockIdx.x;
    const float invN = 1.0f / (float)N_NODES;

    // staging offsets: linear LDS dest, XOR swizzle in the global source
    int srcoff[4], dsto[4];
#pragma unroll
    for (int i = 0; i < 4; ++i) {
        int ci = i * 512 + tid;
        int row = ci >> 4, c = ci & 15;
        srcoff[i] = row * 128 + ((c ^ (row & 15)) * 8);
        dsto[i]   = ci * 8;
    }
    auto stage = [&](const bf16_t* src, bf16_t* dst) {
#pragma unroll
        for (int i = 0; i < 4; ++i)
            gload_lds16(src + srcoff[i], dst + dsto[i]);
    };
    auto xp = [&](int c) { return (c == 0) ? x0 : (c == 1) ? x1 : x2; };

    const int ts = (int)(((long)bid * NTILES) / GRIDG);
    const int te = (int)(((long)(bid + 1) * NTILES) / GRIDG);
    const int nk = (mode == 0) ? 3 : 1;

    f32x4 acc[2][4];

    // ---------------- Phase A: stats only ----------------
    {
        // mode 0: k-major over all 2346 (k,tile) items -> W staged only at k
        // boundaries (~2 per block). mode 1: c-fastest per tile (acc chain).
        int s, e;
        if (mode == 0) {
            s = (int)(((long)bid * (NTILES * 3)) / GRIDG);
            e = (int)(((long)(bid + 1) * (NTILES * 3)) / GRIDG);
        } else {
            s = ts * 3; e = te * 3;
        }
        auto kofA = [&](int w) { return (mode == 0) ? (w / NTILES) : (w % 3); };
        auto tofA = [&](int w) { return (mode == 0) ? (w % NTILES) : (w / 3); };
        auto wslA = [&](int w, int k) { return (mode == 0) ? (k & 1) : (w & 1); };

        {
            int k0 = kofA(s);
            stage(wt + (long)k0 * 16384, lds_w[wslA(s, k0)]);
            stage(xp(k0) + (long)tofA(s) * 16384, lds_x[s & 1]);
        }
        for (int w = s; w < e; ++w) {
            const int ksel = kofA(w), tile = tofA(w);
            const bf16_t* wb = lds_w[wslA(w, ksel)];
            const bf16_t* xb = lds_x[w & 1];

            __syncthreads();                      // drain DMA for item w
            if (w + 1 < e) {
                int kn = kofA(w + 1), tn = tofA(w + 1);
                if (mode == 1 || kn != ksel)
                    stage(wt + (long)kn * 16384, lds_w[wslA(w + 1, kn)]);
                stage(xp(kn) + (long)tn * 16384, lds_x[(w + 1) & 1]);
            }
            if (mode == 0 || ksel == 0) {
#pragma unroll
                for (int a = 0; a < 2; ++a)
#pragma unroll
                    for (int b = 0; b < 4; ++b) acc[a][b] = (f32x4){0.f, 0.f, 0.f, 0.f};
            }
#pragma unroll
            for (int ks = 0; ks < 4; ++ks) {
                bf16x8 xf[4], wf[2];
#pragma unroll
                for (int ms = 0; ms < 4; ++ms) {
                    int row = wr * 64 + ms * 16 + t16;
                    int sw = (ks * 4 + quad) ^ t16;
                    xf[ms] = *(const bf16x8*)&xb[row * 128 + sw * 8];
                }
#pragma unroll
                for (int ns = 0; ns < 2; ++ns) {
                    int row = wc * 32 + ns * 16 + t16;
                    int sw = (ks * 4 + quad) ^ t16;
                    wf[ns] = *(const bf16x8*)&wb[row * 128 + sw * 8];
                }
#pragma unroll
                for (int ns = 0; ns < 2; ++ns)
#pragma unroll
                    for (int ms = 0; ms < 4; ++ms)
                        acc[ns][ms] = __builtin_amdgcn_mfma_f32_16x16x32_bf16(
                            wf[ns], xf[ms], acc[ns][ms], 0, 0, 0);
            }
            if (mode == 0 || ksel == 2) {
                const float* bp = bias + ((mode == 0) ? ksel * 128 : 0);
                float ss[8], sq[8];
#pragma unroll
                for (int i = 0; i < 8; ++i) { ss[i] = 0.f; sq[i] = 0.f; }
#pragma unroll
                for (int ms = 0; ms < 4; ++ms) {
                    long m = (long)tile * 128 + wr * 64 + ms * 16 + t16;
                    if (m < N_NODES) {
#pragma unroll
                        for (int ns = 0; ns < 2; ++ns) {
                            int n0 = wc * 32 + ns * 16 + quad * 4;
                            float4 b4 = *(const float4*)&bp[n0];
                            float v0 = acc[ns][ms][0] + b4.x;
                            float v1 = acc[ns][ms][1] + b4.y;
                            float v2 = acc[ns][ms][2] + b4.z;
                            float v3 = acc[ns][ms][3] + b4.w;
                            ss[ns * 4 + 0] += v0; sq[ns * 4 + 0] += v0 * v0;
                            ss[ns * 4 + 1] += v1; sq[ns * 4 + 1] += v1 * v1;
                            ss[ns * 4 + 2] += v2; sq[ns * 4 + 2] += v2 * v2;
                            ss[ns * 4 + 3] += v3; sq[ns * 4 + 3] += v3 * v3;
                        }
                    }
                }
#pragma unroll
                for (int o = 1; o < 16; o <<= 1) {
#pragma unroll
                    for (int i = 0; i < 8; ++i) {
                        ss[i] += __shfl_xor(ss[i], o);
                        sq[i] += __shfl_xor(sq[i], o);
                    }
                }
                if (t16 == 0) {
#pragma unroll
                    for (int ns = 0; ns < 2; ++ns)
#pragma unroll
                        for (int i = 0; i < 4; ++i) {
                            lsc[w8 * 64 +      ns * 16 + quad * 4 + i] = ss[ns * 4 + i];
                            lsc[w8 * 64 + 32 + ns * 16 + quad * 4 + i] = sq[ns * 4 + i];
                        }
                }
                barrier_lgkm();
                if (tid < 256) {
                    int selo = (tid >> 7) * 32;
                    int d = tid & 127;
                    int wcq = d >> 5, f = d & 31;
                    float v = lsc[wcq * 64 + selo + f] + lsc[(wcq + 4) * 64 + selo + f];
                    int slice = (mode == 0) ? ksel : 0;
                    partial[((long)slice * NTILES + tile) * 256 + tid] = v;
                }
            }
        }
    }

    // ---------------- stats fold + coefficients ----------------
    const int foldblk = (bid < nk * 16);
    grid_bar(cnt + 0, 1, foldblk);             // all release; fold blocks acquire
    if (foldblk && tid < 256) {                // level-1 fold: 49 tiles/block
        int k = bid >> 4, j = bid & 15;
        int b0 = j * 49, b1 = (b0 + 49 < NTILES) ? b0 + 49 : NTILES;
        float s = 0.f;
        const float* pp = partial + (long)k * NTILES * 256 + tid;
        for (int b = b0; b < b1; ++b) s += pp[(long)b * 256];
        tmp[(k * 16 + j) * 256 + tid] = s;
    }
    grid_bar(cnt + 1, foldblk, 1);             // fold blocks release; all acquire
    if (tid < 128) {                           // per-block coef build
        for (int k = 0; k < nk; ++k) {
            float S = 0.f, Q = 0.f;
#pragma unroll
            for (int j = 0; j < 16; ++j) {
                S += tmp[(k * 16 + j) * 256 + tid];
                Q += tmp[(k * 16 + j) * 256 + 128 + tid];
            }
            float mu = S * invN;
            float var = Q * invN - mu * mu;
            float rs = rsqrtf(var + EPS_F);
            float gk = gg[k * 128 + tid], bek = be[k * 128 + tid];
            float bk = bias[k * 128 + tid];
            float wk = (mode == 0) ? wmix[k] : 1.f;
            lsc[k * 256 + tid]       = wk * rs * gk;
            lsc[k * 256 + 128 + tid] = wk * ((bk - mu) * rs * gk + bek);
        }
    }
    __syncthreads();

    // ---------------- Phase B: recompute + emit ----------------
    {
        int tile = ts, c = 0, p = 0;
        const int w0 = ts * 3, w1 = te * 3;
        f32x4 res[2][4];
        stage(wt, lds_w[0]);
        stage(x0 + (long)ts * 16384, lds_x[0]);
        for (int w = w0; w < w1; ++w) {
            __syncthreads();
            int cn = c + 1, tn = tile;
            if (cn == 3) { cn = 0; tn = tile + 1; }
            if (w + 1 < w1) {
                stage(wt + (long)cn * 16384, lds_w[p ^ 1]);
                stage(xp(cn) + (long)tn * 16384, lds_x[p ^ 1]);
            }
            if (mode == 0 || c == 0) {
#pragma unroll
                for (int a = 0; a < 2; ++a)
#pragma unroll
                    for (int b = 0; b < 4; ++b) acc[a][b] = (f32x4){0.f, 0.f, 0.f, 0.f};
            }
            if (mode == 0 && c == 0) {
                if (accflag) {
#pragma unroll
                    for (int ns = 0; ns < 2; ++ns)
#pragma unroll
                        for (int ms = 0; ms < 4; ++ms) {
                            long m = (long)tile * 128 + wr * 64 + ms * 16 + t16;
                            int n0 = wc * 32 + ns * 16 + quad * 4;
                            bf16x4 pv = *(const bf16x4*)&outb[m * 128 + n0];
                            res[ns][ms] = (f32x4){(float)pv[0], (float)pv[1],
                                                  (float)pv[2], (float)pv[3]};
                        }
                } else {
#pragma unroll
                    for (int a = 0; a < 2; ++a)
#pragma unroll
                        for (int b = 0; b < 4; ++b) res[a][b] = (f32x4){0.f, 0.f, 0.f, 0.f};
                }
            }
#pragma unroll
            for (int ks = 0; ks < 4; ++ks) {
                bf16x8 xf[4], wf[2];
#pragma unroll
                for (int ms = 0; ms < 4; ++ms) {
                    int row = wr * 64 + ms * 16 + t16;
                    int sw = (ks * 4 + quad) ^ t16;
                    xf[ms] = *(const bf16x8*)&lds_x[p][row * 128 + sw * 8];
                }
#pragma unroll
                for (int ns = 0; ns < 2; ++ns) {
                    int row = wc * 32 + ns * 16 + t16;
                    int sw = (ks * 4 + quad) ^ t16;
                    wf[ns] = *(const bf16x8*)&lds_w[p][row * 128 + sw * 8];
                }
#pragma unroll
                for (int ns = 0; ns < 2; ++ns)
#pragma unroll
                    for (int ms = 0; ms < 4; ++ms)
                        acc[ns][ms] = __builtin_amdgcn_mfma_f32_16x16x32_bf16(
                            wf[ns], xf[ms], acc[ns][ms], 0, 0, 0);
            }
            if (mode == 0) {
#pragma unroll
                for (int ns = 0; ns < 2; ++ns) {
                    int n0 = wc * 32 + ns * 16 + quad * 4;
                    float4 A4 = *(const float4*)&lsc[c * 256 + n0];
                    float4 B4 = *(const float4*)&lsc[c * 256 + 128 + n0];
#pragma unroll
                    for (int ms = 0; ms < 4; ++ms) {
                        res[ns][ms][0] += fmaxf(acc[ns][ms][0] * A4.x + B4.x, 0.f);
                        res[ns][ms][1] += fmaxf(acc[ns][ms][1] * A4.y + B4.y, 0.f);
                        res[ns][ms][2] += fmaxf(acc[ns][ms][2] * A4.z + B4.z, 0.f);
                        res[ns][ms][3] += fmaxf(acc[ns][ms][3] * A4.w + B4.w, 0.f);
                    }
                }
                if (c == 2) {
#pragma unroll
                    for (int ms = 0; ms < 4; ++ms) {
                        long m = (long)tile * 128 + wr * 64 + ms * 16 + t16;
                        if (m < N_NODES) {
#pragma unroll
                            for (int ns = 0; ns < 2; ++ns) {
                                int n0 = wc * 32 + ns * 16 + quad * 4;
                                bf16x4 ov;
                                ov[0] = (bf16_t)res[ns][ms][0];
                                ov[1] = (bf16_t)res[ns][ms][1];
                                ov[2] = (bf16_t)res[ns][ms][2];
                                ov[3] = (bf16_t)res[ns][ms][3];
                                *(bf16x4*)&outb[m * 128 + n0] = ov;
                            }
                        }
                    }
                }
            } else if (c == 2) {
#pragma unroll
                for (int ms = 0; ms < 4; ++ms) {
                    long m = (long)tile * 128 + wr * 64 + ms * 16 + t16;
                    if (m < N_NODES) {
#pragma unroll
                        for (int ns = 0; ns < 2; ++ns) {
                            int n0 = wc * 32 + ns * 16 + quad * 4;
                            float4 A4 = *(const float4*)&lsc[n0];
                            float4 B4 = *(const float4*)&lsc[128 + n0];
                            float4 o;
                            o.x = fmaxf(acc[ns][ms][0] * A4.x + B4.x, 0.f);
                            o.y = fmaxf(acc[ns][ms][1] * A4.y + B4.y, 0.f);
                            o.z = fmaxf(acc[ns][ms][2] * A4.z + B4.z, 0.f);
                            o.w = fmaxf(acc[ns][ms][3] * A4.w + B4.w, 0.f);
                            *(float4*)&outf[m * 128 + n0] = o;
                        }
                    }
                }
            }
            p ^= 1; c = cn; tile = tn;
        }
    }
}

// ---------------------------------------------------------------------------
extern "C" void kernel_launch(void* const* d_in, const int* in_sizes, int n_in,
                              void* d_out, int out_size, void* d_ws, size_t ws_size,
                              hipStream_t stream)
{
    const float* src_emb = (const float*)d_in[0];
    const float* hr      = (const float*)d_in[1];
    const int*   e_src   = (const int*)d_in[2];
    const int*   e_dst   = (const int*)d_in[3];
    const float* w_zero  = (const float*)d_in[4];
    const float* w_first = (const float*)d_in[5];
    const float* w_mid   = (const float*)d_in[6];
    const float* w_last  = (const float*)d_in[7];
    const float* W_zero  = (const float*)d_in[8];
    const float* b_zero  = (const float*)d_in[9];
    const float* g_zero  = (const float*)d_in[10];
    const float* be_zero = (const float*)d_in[11];
    const float* W_first = (const float*)d_in[12];
    const float* b_first = (const float*)d_in[13];
    const float* g_first = (const float*)d_in[14];
    const float* be_first= (const float*)d_in[15];
    const float* W_mid   = (const float*)d_in[16];
    const float* b_mid   = (const float*)d_in[17];
    const float* g_mid   = (const float*)d_in[18];
    const float* be_mid  = (const float*)d_in[19];
    const float* W_last  = (const float*)d_in[20];
    const float* b_last  = (const float*)d_in[21];
    const float* g_last  = (const float*)d_in[22];
    const float* be_last = (const float*)d_in[23];
    const float* W_cat   = (const float*)d_in[24];
    const float* b_cat   = (const float*)d_in[25];
    const float* g_cat   = (const float*)d_in[26];
    const float* be_cat  = (const float*)d_in[27];
    float* out = (float*)d_out;

    char* ws = (char*)d_ws;
    size_t off = 0;
    auto carve = [&](size_t bytes) -> char* {
        off = (off + 255) & ~(size_t)255;
        char* p = ws + off;
        off += bytes;
        return p;
    };

    const size_t SB = (size_t)NPAD * 128 * sizeof(bf16_t);
    bf16_t* B[8];
    for (int i = 0; i < 8; ++i) B[i] = (bf16_t*)carve(SB);
    bf16_t* wt    = (bf16_t*)carve((size_t)27 * 16384 * 2);
    float*  partial = (float*)carve((size_t)3 * NTILES * 256 * sizeof(float));
    float*  tmp   = (float*)carve((size_t)48 * 256 * sizeof(float));
    int* cnts   = (int*)carve(32 * 4);
    int* deg    = (int*)carve((size_t)N_NODES * 4);
    int* rowp   = (int*)carve((size_t)(N_NODES + 1) * 4);
    int* cursor = (int*)carve((size_t)N_NODES * 4);
    int* csr    = (int*)carve((size_t)N_EDGES * 4);
    int* parts  = (int*)carve(SCAN_B * 4);
    int* pofs   = (int*)carve(SCAN_B * 4);

    bf16_t* wtZ  = wt;
    bf16_t* wtF0 = wt + (size_t)3  * 16384;
    bf16_t* wtF1 = wt + (size_t)6  * 16384;
    bf16_t* wtF2 = wt + (size_t)9  * 16384;
    bf16_t* wtM0 = wt + (size_t)12 * 16384;
    bf16_t* wtM1 = wt + (size_t)15 * 16384;
    bf16_t* wtL0 = wt + (size_t)18 * 16384;
    bf16_t* wtL1 = wt + (size_t)21 * 16384;
    bf16_t* wtC  = wt + (size_t)24 * 16384;

    const int GEL8 = (N_NODES * 128) / 2048;   // 6250, exact

    init_zero_kernel<<<dim3((N_NODES + 255) / 256), dim3(256), 0, stream>>>(deg, cnts);
    transpose_w_kernel<<<dim3(1728), dim3(256), 0, stream>>>(W_zero, W_first, W_mid, W_last, W_cat, wt);
    deg_count_kernel<<<dim3((N_EDGES + 255) / 256), dim3(256), 0, stream>>>(e_dst, deg);
    scan_a_kernel<<<dim3(SCAN_B), dim3(256), 0, stream>>>(deg, parts);
    scan_b_kernel<<<dim3(1), dim3(64), 0, stream>>>(parts, pofs);
    scan_c_kernel<<<dim3(SCAN_B), dim3(256), 0, stream>>>(deg, pofs, rowp, cursor);
    scatter_kernel<<<dim3((N_EDGES + 255) / 256), dim3(256), 0, stream>>>(e_src, e_dst, cursor, csr);

    auto M = [&](const bf16_t* x0_, const bf16_t* x1_, const bf16_t* x2_,
                 const bf16_t* w_, const float* b_, const float* g_, const float* be_,
                 const float* wm_, bf16_t* ob_, float* of_, int acc_, int mode_, int id) {
        mixed_kernel<<<dim3(GRIDG), dim3(512), 0, stream>>>(
            x0_, x1_, x2_, w_, b_, g_, be_, wm_, ob_, of_,
            partial, tmp, cnts + id * 2, mode_, acc_);
    };
    auto A = [&](const bf16_t* h_, bf16_t* me_, bf16_t* mx_) {
        agg_kernel<<<dim3(N_NODES / 16), dim3(256), 0, stream>>>(h_, rowp, csr, me_, mx_);
    };

    // zero op: pre -> B3,B4,B5 ; h_in = B6
    pre_kernel<<<dim3(GEL8), dim3(256), 0, stream>>>(src_emb, hr, B[3], B[4], B[5]);
    M(B[3], B[4], B[5], wtZ, b_zero, g_zero, be_zero, w_zero, B[6], nullptr, 0, 0, 0);

    A(B[6], B[3], B[4]);                                             // aggH -> B3,B4

    // s0 = mixed([h_in, aggH], first0)                              // s0 = B5
    M(B[6], B[3], B[4], wtF0, b_first + 0, g_first + 0, be_first + 0,
      w_first + 0, B[5], nullptr, 0, 0, 1);
    // s1 (h_in contribution first)                                  // s1 = B7
    M(B[6], B[3], B[4], wtF1, b_first + 384, g_first + 384, be_first + 384,
      w_first + 3, B[7], nullptr, 0, 0, 2);
    // h_in(B6), aggH(B3,B4) dead

    A(B[5], B[3], B[4]);                                             // aggS0 -> B3,B4

    // s1 += mixed([s0, aggS0], first2)
    M(B[5], B[3], B[4], wtF2, b_first + 768, g_first + 768, be_first + 768,
      w_first + 6, B[7], nullptr, 1, 0, 3);
    // m0 = mixed([s0, aggS0], mid0)                                 // m0 = B6
    M(B[5], B[3], B[4], wtM0, b_mid + 0, g_mid + 0, be_mid + 0,
      w_mid + 0, B[6], nullptr, 0, 0, 4);
    // s0(B5), aggS0(B3,B4) dead

    A(B[7], B[3], B[4]);                                             // aggS1 -> B3,B4

    // m1 = mixed([s1, aggS1], mid1)                                 // m1 = B5
    M(B[7], B[3], B[4], wtM1, b_mid + 384, g_mid + 384, be_mid + 384,
      w_mid + 3, B[5], nullptr, 0, 0, 5);
    // s1(B7), aggS1(B3,B4) dead

    // s_last = mixed([m0, agg m0], last0) + mixed([m1, agg m1], last1)  // sl = B7
    A(B[6], B[3], B[4]);
    M(B[6], B[3], B[4], wtL0, b_last + 0, g_last + 0, be_last + 0,
      w_last + 0, B[7], nullptr, 0, 0, 6);
    A(B[5], B[3], B[4]);
    M(B[5], B[3], B[4], wtL1, b_last + 384, g_last + 384, be_last + 384,
      w_last + 3, B[7], nullptr, 1, 0, 7);

    // out = relu(norm([m0 | m1 | s_last] @ W_cat + b_cat)) directly to fp32
    M(B[6], B[5], B[7], wtC, b_cat, g_cat, be_cat, nullptr,
      nullptr, out, 0, 1, 8);
}

// Round 5
// 1163.195 us; speedup vs baseline: 2.2191x; 1.1038x over previous
//
#include <hip/hip_runtime.h>

#define N_NODES 100000
#define N_EDGES 600000
#define NPAD    100096      // 782 * 128
#define NTILES  782
#define SCAN_B  98          // ceil(100000/1024)
#define EPS_F   1e-5f
#define GRIDG   256         // persistent mixed grid: 1 block (8 waves) per CU

typedef __bf16 bf16_t;
typedef __bf16 bf16x8 __attribute__((ext_vector_type(8)));
typedef __bf16 bf16x4 __attribute__((ext_vector_type(4)));
typedef float  f32x4  __attribute__((ext_vector_type(4)));

// ---------------------------------------------------------------------------
// zero deg + grid-barrier counters
__global__ __launch_bounds__(256)
void init_zero_kernel(int* __restrict__ deg, int* __restrict__ cnt)
{
    int i = blockIdx.x * 256 + threadIdx.x;
    if (i < N_NODES) deg[i] = 0;
    if (i < 32) cnt[i] = 0;
}

// ---------------------------------------------------------------------------
// Weight pre-transpose: WT[mat][n][k] = W[mat][k][n], fp32 -> bf16.
__global__ __launch_bounds__(256)
void transpose_w_kernel(const float* __restrict__ Wz, const float* __restrict__ Wf,
                        const float* __restrict__ Wm, const float* __restrict__ Wl,
                        const float* __restrict__ Wc, bf16_t* __restrict__ wt)
{
    int idx = blockIdx.x * 256 + threadIdx.x;      // < 27*16384, exact grid
    int mat = idx >> 14;
    int off = idx & 16383;
    int n = off >> 7, kk = off & 127;
    const float* src;
    if      (mat < 3)  src = Wz + mat * 16384;
    else if (mat < 12) src = Wf + (mat - 3) * 16384;
    else if (mat < 18) src = Wm + (mat - 12) * 16384;
    else if (mat < 24) src = Wl + (mat - 18) * 16384;
    else               src = Wc + (mat - 24) * 16384;
    wt[idx] = (bf16_t)src[kk * 128 + n];
}

// ---------------------------------------------------------------------------
// pre-candidates, vectorized 8 elems/thread: [se, se-hr, se*hr] as bf16
__global__ __launch_bounds__(256)
void pre_kernel(const float* __restrict__ se, const float* __restrict__ hr,
                bf16_t* __restrict__ p0, bf16_t* __restrict__ p1, bf16_t* __restrict__ p2)
{
    long i = ((long)blockIdx.x * 256 + threadIdx.x) * 8;   // grid exact: N*128/2048
    float4 a0 = *(const float4*)&se[i], a1 = *(const float4*)&se[i + 4];
    float4 b0 = *(const float4*)&hr[i], b1 = *(const float4*)&hr[i + 4];
    float av[8] = {a0.x, a0.y, a0.z, a0.w, a1.x, a1.y, a1.z, a1.w};
    float bv[8] = {b0.x, b0.y, b0.z, b0.w, b1.x, b1.y, b1.z, b1.w};
    bf16x8 o0, o1, o2;
#pragma unroll
    for (int j = 0; j < 8; ++j) {
        o0[j] = (bf16_t)av[j];
        o1[j] = (bf16_t)(av[j] - bv[j]);
        o2[j] = (bf16_t)(av[j] * bv[j]);
    }
    *(bf16x8*)&p0[i] = o0;
    *(bf16x8*)&p1[i] = o1;
    *(bf16x8*)&p2[i] = o2;
}

// ---------------------------------------------------------------------------
// CSR build
__global__ __launch_bounds__(256)
void deg_count_kernel(const int* __restrict__ dst, int* __restrict__ deg)
{
    int i = blockIdx.x * 256 + threadIdx.x;
    if (i < N_EDGES) atomicAdd(&deg[dst[i]], 1);
}

__global__ __launch_bounds__(256)
void scan_a_kernel(const int* __restrict__ deg, int* __restrict__ partials)
{
    __shared__ int ls[256];
    int b = blockIdx.x, t = threadIdx.x;
    int s = 0;
    for (int j = 0; j < 4; ++j) {
        int i = b * 1024 + t * 4 + j;
        if (i < N_NODES) s += deg[i];
    }
    ls[t] = s; __syncthreads();
    for (int o = 128; o > 0; o >>= 1) {
        if (t < o) ls[t] += ls[t + o];
        __syncthreads();
    }
    if (t == 0) partials[b] = ls[0];
}

__global__ void scan_b_kernel(const int* __restrict__ partials, int* __restrict__ pofs)
{
    if (threadIdx.x == 0) {
        int a = 0;
        for (int i = 0; i < SCAN_B; ++i) { pofs[i] = a; a += partials[i]; }
    }
}

__global__ __launch_bounds__(256)
void scan_c_kernel(const int* __restrict__ deg, const int* __restrict__ pofs,
                   int* __restrict__ row_ptr, int* __restrict__ cursor)
{
    __shared__ int ls[256];
    int b = blockIdx.x, t = threadIdx.x;
    int v[4], s = 0;
    for (int j = 0; j < 4; ++j) {
        int i = b * 1024 + t * 4 + j;
        v[j] = (i < N_NODES) ? deg[i] : 0;
        s += v[j];
    }
    ls[t] = s; __syncthreads();
    for (int o = 1; o < 256; o <<= 1) {
        int tv = (t >= o) ? ls[t - o] : 0;
        __syncthreads();
        ls[t] += tv;
        __syncthreads();
    }
    int excl = ls[t] - s + pofs[b];
    for (int j = 0; j < 4; ++j) {
        int i = b * 1024 + t * 4 + j;
        if (i < N_NODES) { row_ptr[i] = excl; cursor[i] = excl; excl += v[j]; }
    }
    if (b == 0 && t == 0) row_ptr[N_NODES] = N_EDGES;
}

__global__ __launch_bounds__(256)
void scatter_kernel(const int* __restrict__ src, const int* __restrict__ dst,
                    int* __restrict__ cursor, int* __restrict__ csr_src)
{
    int i = blockIdx.x * 256 + threadIdx.x;
    if (i < N_EDGES) {
        int p = atomicAdd(&cursor[dst[i]], 1);
        csr_src[p] = src[i];
    }
}

// ---------------------------------------------------------------------------
// mean + max aggregation. 16 lanes per node, 16B loads per lane per edge.
__global__ __launch_bounds__(256)
void agg_kernel(const bf16_t* __restrict__ h, const int* __restrict__ row_ptr,
                const int* __restrict__ csr_src,
                bf16_t* __restrict__ mean_o, bf16_t* __restrict__ max_o)
{
    int node = blockIdx.x * 16 + (threadIdx.x >> 4);   // grid exact: N/16
    int dd = (threadIdx.x & 15) * 8;
    int e0 = row_ptr[node], e1 = row_ptr[node + 1];
    float s[8], mx[8];
#pragma unroll
    for (int j = 0; j < 8; ++j) { s[j] = 0.f; mx[j] = 0.f; }
    for (int e = e0; e < e1; ++e) {
        int sc = csr_src[e];
        bf16x8 v = *(const bf16x8*)&h[(long)sc * 128 + dd];
#pragma unroll
        for (int j = 0; j < 8; ++j) {
            float f = (float)v[j];
            s[j] += f;
            mx[j] = fmaxf(mx[j], f);
        }
    }
    float inv = 1.f / fmaxf((float)(e1 - e0), 1.f);
    bf16x8 om, ox;
#pragma unroll
    for (int j = 0; j < 8; ++j) { om[j] = (bf16_t)(s[j] * inv); ox[j] = (bf16_t)mx[j]; }
    *(bf16x8*)&mean_o[(long)node * 128 + dd] = om;
    *(bf16x8*)&max_o [(long)node * 128 + dd] = ox;
}

// ---------------------------------------------------------------------------
// async global->LDS, 16B per lane. LDS dest must be wave-uniform base + lane*16.
__device__ __forceinline__ void gload_lds16(const bf16_t* g, bf16_t* l)
{
    __builtin_amdgcn_global_load_lds(
        (const __attribute__((address_space(1))) void*)g,
        (__attribute__((address_space(3))) void*)l, 16, 0, 0);
}

// lgkm-only barrier: orders LDS writes->reads across waves WITHOUT draining vmcnt.
__device__ __forceinline__ void barrier_lgkm()
{
    asm volatile("s_waitcnt lgkmcnt(0)" ::: "memory");
    __builtin_amdgcn_s_barrier();
    asm volatile("" ::: "memory");
}

// device-wide barrier (R4-proven): RELAXED spin (no per-iteration cache inv),
// one release fence pre-arrival, one acquire fence post-exit, only where used.
// SAFETY: LDS>80KB => 1 block/CU; grid==256==#CUs => co-resident by construction.
__device__ __forceinline__ void grid_bar(int* c, int do_rel, int do_acq)
{
    __syncthreads();
    if (threadIdx.x == 0) {
        if (do_rel) __builtin_amdgcn_fence(__ATOMIC_RELEASE, "agent");
        __hip_atomic_fetch_add(c, 1, __ATOMIC_RELAXED, __HIP_MEMORY_SCOPE_AGENT);
        while (__hip_atomic_load(c, __ATOMIC_RELAXED, __HIP_MEMORY_SCOPE_AGENT) < GRIDG)
            __builtin_amdgcn_s_sleep(16);
        if (do_acq) __builtin_amdgcn_fence(__ATOMIC_ACQUIRE, "agent");
    }
    __syncthreads();
}

// ---------------------------------------------------------------------------
// Fused mixed-op kernel, v2 (depth-3 DMA ring, T3/T4 counted vmcnt):
//   - x ring of 4 x 32KB LDS slots; loop top: vmcnt(8) -> s_barrier -> issue
//     stage(w+3). 3 stages in flight hide the ~1.3us/item DMA. vmcnt counts
//     are exact in phase A because the steady loop's ONLY VMEM is our DMAs:
//   - W in REGISTERS (wreg[3][2][4], static idx; 96 VGPR) loaded from global
//     once (L2-hot). No W staging in the loop. (R1's spill was the
//     launch_bounds(256,2)=128-VGPR cap; (512,1) allows 256.)
//   - stats in registers: ssA/sqA[3][8] accumulate RAW acc (bias folded
//     analytically at coef build: mu+=b, var unchanged). One cross-lane
//     reduce + one partial store per block at phase A end.
// Phase A: stats (mode 0: item-balanced ranges; mode 1: tile-aligned, acc
//   carried over c). grid_bar -> 16*nk-block fold -> grid_bar -> coefs in lsc.
// Phase B: tile-major recompute, emit state=sum_c relu(A_c*acc+B_c) bf16
//   (mode 0) or final fp32 (mode 1).
__global__ __launch_bounds__(512, 1)
void mixed_kernel(const bf16_t* __restrict__ x0, const bf16_t* __restrict__ x1,
                  const bf16_t* __restrict__ x2, const bf16_t* __restrict__ wt,
                  const float* __restrict__ bias, const float* __restrict__ gg,
                  const float* __restrict__ be, const float* __restrict__ wmix,
                  bf16_t* __restrict__ outb, float* __restrict__ outf,
                  float* __restrict__ partial, float* __restrict__ tmp,
                  int* __restrict__ cnt, int mode, int accflag)
{
    __shared__ __align__(16) bf16_t lds_x[4][16384];   // x ring (4 x 32 KB)
    __shared__ float lsc[768];                         // lred / coefs

    const int tid  = threadIdx.x;
    const int lane = tid & 63;
    const int w8   = tid >> 6;
    const int quad = lane >> 4;
    const int t16  = lane & 15;
    const int wr = w8 >> 2, wc = w8 & 3;
    const int bid = blockIdx.x;
    const float invN = 1.0f / (float)N_NODES;

    // staging offsets: linear LDS dest, XOR swizzle in the global source
    int srcoff[4], dsto[4];
#pragma unroll
    for (int i = 0; i < 4; ++i) {
        int ci = i * 512 + tid;
        int row = ci >> 4, c = ci & 15;
        srcoff[i] = row * 128 + ((c ^ (row & 15)) * 8);
        dsto[i]   = ci * 8;
    }
    auto stage = [&](const bf16_t* src, int slot) {
#pragma unroll
        for (int i = 0; i < 4; ++i)
            gload_lds16(src + srcoff[i], &lds_x[slot][dsto[i]]);
    };
    auto xp = [&](int c) { return (c == 0) ? x0 : (c == 1) ? x1 : x2; };

    // W fragments to registers (global, L2-hot; swizzle-free layout)
    bf16x8 wreg[3][2][4];
#pragma unroll
    for (int c = 0; c < 3; ++c)
#pragma unroll
        for (int ns = 0; ns < 2; ++ns)
#pragma unroll
            for (int ks = 0; ks < 4; ++ks)
                wreg[c][ns][ks] = *(const bf16x8*)
                    &wt[(long)c * 16384 + (wc * 32 + ns * 16 + t16) * 128
                        + ks * 32 + quad * 8];

    const int ts = (int)(((long)bid * NTILES) / GRIDG);
    const int te = (int)(((long)(bid + 1) * NTILES) / GRIDG);
    const int nk = (mode == 0) ? 3 : 1;

    f32x4 acc[2][4];
    float ssA[3][8], sqA[3][8];
#pragma unroll
    for (int k = 0; k < 3; ++k)
#pragma unroll
        for (int i = 0; i < 8; ++i) { ssA[k][i] = 0.f; sqA[k][i] = 0.f; }

#define ZACC() do { \
    _Pragma("unroll") for (int a_ = 0; a_ < 2; ++a_) \
    _Pragma("unroll") for (int b_ = 0; b_ < 4; ++b_) \
        acc[a_][b_] = (f32x4){0.f, 0.f, 0.f, 0.f}; } while (0)

#define MMAC(C) do { \
    _Pragma("unroll") for (int ks = 0; ks < 4; ++ks) { \
        bf16x8 xf[4]; \
        _Pragma("unroll") for (int ms = 0; ms < 4; ++ms) { \
            int row_ = wr * 64 + ms * 16 + t16; \
            int sw_ = (ks * 4 + quad) ^ t16; \
            xf[ms] = *(const bf16x8*)&lds_x[slot][row_ * 128 + sw_ * 8]; \
        } \
        _Pragma("unroll") for (int ns = 0; ns < 2; ++ns) \
        _Pragma("unroll") for (int ms = 0; ms < 4; ++ms) \
            acc[ns][ms] = __builtin_amdgcn_mfma_f32_16x16x32_bf16( \
                wreg[C][ns][ks], xf[ms], acc[ns][ms], 0, 0, 0); \
    } } while (0)

#define ACCST(K) do { \
    _Pragma("unroll") for (int ms = 0; ms < 4; ++ms) { \
        long m_ = (long)tile * 128 + wr * 64 + ms * 16 + t16; \
        if (m_ < N_NODES) { \
            _Pragma("unroll") for (int ns = 0; ns < 2; ++ns) \
            _Pragma("unroll") for (int j_ = 0; j_ < 4; ++j_) { \
                float v_ = acc[ns][ms][j_]; \
                ssA[K][ns * 4 + j_] += v_; \
                sqA[K][ns * 4 + j_] += v_ * v_; \
            } \
        } \
    } } while (0)

#define RINGWAIT(w_, e_) do { \
    int ah_ = (e_) - 1 - (w_); \
    if (ah_ >= 2)      asm volatile("s_waitcnt vmcnt(8)" ::: "memory"); \
    else if (ah_ == 1) asm volatile("s_waitcnt vmcnt(4)" ::: "memory"); \
    else               asm volatile("s_waitcnt vmcnt(0)" ::: "memory"); \
    __builtin_amdgcn_sched_barrier(0); \
    __builtin_amdgcn_s_barrier(); \
    __builtin_amdgcn_sched_barrier(0); } while (0)

    // ---------------- Phase A: stats only ----------------
    {
        int sA, eA;
        if (mode == 0) {   // item-balanced (items independent)
            sA = (int)(((long)bid * (NTILES * 3)) / GRIDG);
            eA = (int)(((long)(bid + 1) * (NTILES * 3)) / GRIDG);
        } else {           // tile-aligned (acc chained over c)
            sA = ts * 3; eA = te * 3;
        }
#pragma unroll 1
        for (int i = 0; i < 3; ++i)
            if (sA + i < eA) stage(xp((sA + i) % 3) + (long)((sA + i) / 3) * 16384,
                                   (sA + i) & 3);
#pragma unroll 1
        for (int w = sA; w < eA; ++w) {
            const int c = w % 3, tile = w / 3, slot = w & 3;
            RINGWAIT(w, eA);
            if (w + 3 < eA)
                stage(xp((w + 3) % 3) + (long)((w + 3) / 3) * 16384, (w + 3) & 3);
            if (mode == 0 || c == 0) ZACC();
            if (c == 0) MMAC(0); else if (c == 1) MMAC(1); else MMAC(2);
            if (mode == 0) {
                if (c == 0) ACCST(0); else if (c == 1) ACCST(1); else ACCST(2);
            } else if (c == 2) ACCST(0);
        }
    }

    // block-level stats reduce: shfl over the 16 lanes of each t16 group
#pragma unroll
    for (int o = 1; o < 16; o <<= 1)
#pragma unroll
        for (int k = 0; k < 3; ++k)
#pragma unroll
            for (int i = 0; i < 8; ++i) {
                ssA[k][i] += __shfl_xor(ssA[k][i], o);
                sqA[k][i] += __shfl_xor(sqA[k][i], o);
            }
#pragma unroll 1
    for (int k = 0; k < nk; ++k) {
        barrier_lgkm();                        // lsc reuse fence
        if (t16 == 0) {
#pragma unroll
            for (int ns = 0; ns < 2; ++ns)
#pragma unroll
                for (int i = 0; i < 4; ++i) {
                    float s_, q_;
                    if (k == 0)      { s_ = ssA[0][ns*4+i]; q_ = sqA[0][ns*4+i]; }
                    else if (k == 1) { s_ = ssA[1][ns*4+i]; q_ = sqA[1][ns*4+i]; }
                    else             { s_ = ssA[2][ns*4+i]; q_ = sqA[2][ns*4+i]; }
                    lsc[w8 * 64 +      ns * 16 + quad * 4 + i] = s_;
                    lsc[w8 * 64 + 32 + ns * 16 + quad * 4 + i] = q_;
                }
        }
        barrier_lgkm();
        if (tid < 256) {
            int selo = (tid >> 7) * 32;
            int d = tid & 127;
            int wcq = d >> 5, f = d & 31;
            float v = lsc[wcq * 64 + selo + f] + lsc[(wcq + 4) * 64 + selo + f];
            partial[((long)k * GRIDG + bid) * 256 + tid] = v;
        }
    }

    // ---------------- stats fold + coefficients ----------------
    const int foldblk = (bid < nk * 16);
    grid_bar(cnt + 0, 1, foldblk);
    if (foldblk && tid < 256) {                // sum 16 block-rows each
        int k = bid >> 4, j = bid & 15;
        float s = 0.f;
        const float* pp = partial + ((long)k * GRIDG + j * 16) * 256 + tid;
#pragma unroll
        for (int b = 0; b < 16; ++b) s += pp[(long)b * 256];
        tmp[(k * 16 + j) * 256 + tid] = s;
    }
    grid_bar(cnt + 1, foldblk, 1);
    if (tid < 128) {                           // per-block coef build
        for (int k = 0; k < nk; ++k) {
            float S = 0.f, Q = 0.f;
#pragma unroll
            for (int j = 0; j < 16; ++j) {
                S += tmp[(k * 16 + j) * 256 + tid];
                Q += tmp[(k * 16 + j) * 256 + 128 + tid];
            }
            float sa  = S * invN;              // mean of raw acc
            float var = Q * invN - sa * sa;    // bias shift: variance unchanged
            float rs  = rsqrtf(var + EPS_F);
            float gk = gg[k * 128 + tid], bek = be[k * 128 + tid];
            float wk = (mode == 0) ? wmix[k] : 1.f;
            lsc[k * 256 + tid]       = wk * rs * gk;              // A
            lsc[k * 256 + 128 + tid] = wk * (-sa * rs * gk + bek);// B (b-mu=-sa)
        }
    }
    __syncthreads();

    // ---------------- Phase B: recompute + emit ----------------
    {
        const int w0 = ts * 3, w1 = te * 3;
        f32x4 res[2][4];
#pragma unroll 1
        for (int i = 0; i < 3; ++i)
            if (w0 + i < w1) stage(xp((w0 + i) % 3) + (long)((w0 + i) / 3) * 16384,
                                   (w0 + i) & 3);
#pragma unroll 1
        for (int w = w0; w < w1; ++w) {
            const int c = w % 3, tile = w / 3, slot = w & 3;
            RINGWAIT(w, w1);
            if (w + 3 < w1)
                stage(xp((w + 3) % 3) + (long)((w + 3) / 3) * 16384, (w + 3) & 3);
            if (mode == 0 || c == 0) ZACC();
            if (mode == 0 && c == 0) {
                if (accflag) {
#pragma unroll
                    for (int ns = 0; ns < 2; ++ns)
#pragma unroll
                        for (int ms = 0; ms < 4; ++ms) {
                            long m = (long)tile * 128 + wr * 64 + ms * 16 + t16;
                            int n0 = wc * 32 + ns * 16 + quad * 4;
                            bf16x4 pv = *(const bf16x4*)&outb[m * 128 + n0];
                            res[ns][ms] = (f32x4){(float)pv[0], (float)pv[1],
                                                  (float)pv[2], (float)pv[3]};
                        }
                } else {
#pragma unroll
                    for (int a = 0; a < 2; ++a)
#pragma unroll
                        for (int b = 0; b < 4; ++b) res[a][b] = (f32x4){0.f, 0.f, 0.f, 0.f};
                }
            }
            if (c == 0) MMAC(0); else if (c == 1) MMAC(1); else MMAC(2);

            if (mode == 0) {
#pragma unroll
                for (int ns = 0; ns < 2; ++ns) {
                    int n0 = wc * 32 + ns * 16 + quad * 4;
                    float4 A4 = *(const float4*)&lsc[c * 256 + n0];
                    float4 B4 = *(const float4*)&lsc[c * 256 + 128 + n0];
#pragma unroll
                    for (int ms = 0; ms < 4; ++ms) {
                        res[ns][ms][0] += fmaxf(acc[ns][ms][0] * A4.x + B4.x, 0.f);
                        res[ns][ms][1] += fmaxf(acc[ns][ms][1] * A4.y + B4.y, 0.f);
                        res[ns][ms][2] += fmaxf(acc[ns][ms][2] * A4.z + B4.z, 0.f);
                        res[ns][ms][3] += fmaxf(acc[ns][ms][3] * A4.w + B4.w, 0.f);
                    }
                }
                if (c == 2) {
#pragma unroll
                    for (int ms = 0; ms < 4; ++ms) {
                        long m = (long)tile * 128 + wr * 64 + ms * 16 + t16;
                        if (m < N_NODES) {
#pragma unroll
                            for (int ns = 0; ns < 2; ++ns) {
                                int n0 = wc * 32 + ns * 16 + quad * 4;
                                bf16x4 ov;
                                ov[0] = (bf16_t)res[ns][ms][0];
                                ov[1] = (bf16_t)res[ns][ms][1];
                                ov[2] = (bf16_t)res[ns][ms][2];
                                ov[3] = (bf16_t)res[ns][ms][3];
                                *(bf16x4*)&outb[m * 128 + n0] = ov;
                            }
                        }
                    }
                }
            } else if (c == 2) {
#pragma unroll
                for (int ms = 0; ms < 4; ++ms) {
                    long m = (long)tile * 128 + wr * 64 + ms * 16 + t16;
                    if (m < N_NODES) {
#pragma unroll
                        for (int ns = 0; ns < 2; ++ns) {
                            int n0 = wc * 32 + ns * 16 + quad * 4;
                            float4 A4 = *(const float4*)&lsc[n0];
                            float4 B4 = *(const float4*)&lsc[128 + n0];
                            float4 o;
                            o.x = fmaxf(acc[ns][ms][0] * A4.x + B4.x, 0.f);
                            o.y = fmaxf(acc[ns][ms][1] * A4.y + B4.y, 0.f);
                            o.z = fmaxf(acc[ns][ms][2] * A4.z + B4.z, 0.f);
                            o.w = fmaxf(acc[ns][ms][3] * A4.w + B4.w, 0.f);
                            *(float4*)&outf[m * 128 + n0] = o;
                        }
                    }
                }
            }
        }
    }
#undef ZACC
#undef MMAC
#undef ACCST
#undef RINGWAIT
}

// ---------------------------------------------------------------------------
extern "C" void kernel_launch(void* const* d_in, const int* in_sizes, int n_in,
                              void* d_out, int out_size, void* d_ws, size_t ws_size,
                              hipStream_t stream)
{
    const float* src_emb = (const float*)d_in[0];
    const float* hr      = (const float*)d_in[1];
    const int*   e_src   = (const int*)d_in[2];
    const int*   e_dst   = (const int*)d_in[3];
    const float* w_zero  = (const float*)d_in[4];
    const float* w_first = (const float*)d_in[5];
    const float* w_mid   = (const float*)d_in[6];
    const float* w_last  = (const float*)d_in[7];
    const float* W_zero  = (const float*)d_in[8];
    const float* b_zero  = (const float*)d_in[9];
    const float* g_zero  = (const float*)d_in[10];
    const float* be_zero = (const float*)d_in[11];
    const float* W_first = (const float*)d_in[12];
    const float* b_first = (const float*)d_in[13];
    const float* g_first = (const float*)d_in[14];
    const float* be_first= (const float*)d_in[15];
    const float* W_mid   = (const float*)d_in[16];
    const float* b_mid   = (const float*)d_in[17];
    const float* g_mid   = (const float*)d_in[18];
    const float* be_mid  = (const float*)d_in[19];
    const float* W_last  = (const float*)d_in[20];
    const float* b_last  = (const float*)d_in[21];
    const float* g_last  = (const float*)d_in[22];
    const float* be_last = (const float*)d_in[23];
    const float* W_cat   = (const float*)d_in[24];
    const float* b_cat   = (const float*)d_in[25];
    const float* g_cat   = (const float*)d_in[26];
    const float* be_cat  = (const float*)d_in[27];
    float* out = (float*)d_out;

    char* ws = (char*)d_ws;
    size_t off = 0;
    auto carve = [&](size_t bytes) -> char* {
        off = (off + 255) & ~(size_t)255;
        char* p = ws + off;
        off += bytes;
        return p;
    };

    const size_t SB = (size_t)NPAD * 128 * sizeof(bf16_t);
    bf16_t* B[8];
    for (int i = 0; i < 8; ++i) B[i] = (bf16_t*)carve(SB);
    bf16_t* wt    = (bf16_t*)carve((size_t)27 * 16384 * 2);
    float*  partial = (float*)carve((size_t)3 * GRIDG * 256 * sizeof(float));
    float*  tmp   = (float*)carve((size_t)48 * 256 * sizeof(float));
    int* cnts   = (int*)carve(32 * 4);
    int* deg    = (int*)carve((size_t)N_NODES * 4);
    int* rowp   = (int*)carve((size_t)(N_NODES + 1) * 4);
    int* cursor = (int*)carve((size_t)N_NODES * 4);
    int* csr    = (int*)carve((size_t)N_EDGES * 4);
    int* parts  = (int*)carve(SCAN_B * 4);
    int* pofs   = (int*)carve(SCAN_B * 4);

    bf16_t* wtZ  = wt;
    bf16_t* wtF0 = wt + (size_t)3  * 16384;
    bf16_t* wtF1 = wt + (size_t)6  * 16384;
    bf16_t* wtF2 = wt + (size_t)9  * 16384;
    bf16_t* wtM0 = wt + (size_t)12 * 16384;
    bf16_t* wtM1 = wt + (size_t)15 * 16384;
    bf16_t* wtL0 = wt + (size_t)18 * 16384;
    bf16_t* wtL1 = wt + (size_t)21 * 16384;
    bf16_t* wtC  = wt + (size_t)24 * 16384;

    const int GEL8 = (N_NODES * 128) / 2048;   // 6250, exact

    init_zero_kernel<<<dim3((N_NODES + 255) / 256), dim3(256), 0, stream>>>(deg, cnts);
    transpose_w_kernel<<<dim3(1728), dim3(256), 0, stream>>>(W_zero, W_first, W_mid, W_last, W_cat, wt);
    deg_count_kernel<<<dim3((N_EDGES + 255) / 256), dim3(256), 0, stream>>>(e_dst, deg);
    scan_a_kernel<<<dim3(SCAN_B), dim3(256), 0, stream>>>(deg, parts);
    scan_b_kernel<<<dim3(1), dim3(64), 0, stream>>>(parts, pofs);
    scan_c_kernel<<<dim3(SCAN_B), dim3(256), 0, stream>>>(deg, pofs, rowp, cursor);
    scatter_kernel<<<dim3((N_EDGES + 255) / 256), dim3(256), 0, stream>>>(e_src, e_dst, cursor, csr);

    auto M = [&](const bf16_t* x0_, const bf16_t* x1_, const bf16_t* x2_,
                 const bf16_t* w_, const float* b_, const float* g_, const float* be_,
                 const float* wm_, bf16_t* ob_, float* of_, int acc_, int mode_, int id) {
        mixed_kernel<<<dim3(GRIDG), dim3(512), 0, stream>>>(
            x0_, x1_, x2_, w_, b_, g_, be_, wm_, ob_, of_,
            partial, tmp, cnts + id * 2, mode_, acc_);
    };
    auto A = [&](const bf16_t* h_, bf16_t* me_, bf16_t* mx_) {
        agg_kernel<<<dim3(N_NODES / 16), dim3(256), 0, stream>>>(h_, rowp, csr, me_, mx_);
    };

    // zero op: pre -> B3,B4,B5 ; h_in = B6
    pre_kernel<<<dim3(GEL8), dim3(256), 0, stream>>>(src_emb, hr, B[3], B[4], B[5]);
    M(B[3], B[4], B[5], wtZ, b_zero, g_zero, be_zero, w_zero, B[6], nullptr, 0, 0, 0);

    A(B[6], B[3], B[4]);                                             // aggH -> B3,B4

    // s0 = mixed([h_in, aggH], first0)                              // s0 = B5
    M(B[6], B[3], B[4], wtF0, b_first + 0, g_first + 0, be_first + 0,
      w_first + 0, B[5], nullptr, 0, 0, 1);
    // s1 (h_in contribution first)                                  // s1 = B7
    M(B[6], B[3], B[4], wtF1, b_first + 384, g_first + 384, be_first + 384,
      w_first + 3, B[7], nullptr, 0, 0, 2);
    // h_in(B6), aggH(B3,B4) dead

    A(B[5], B[3], B[4]);                                             // aggS0 -> B3,B4

    // s1 += mixed([s0, aggS0], first2)
    M(B[5], B[3], B[4], wtF2, b_first + 768, g_first + 768, be_first + 768,
      w_first + 6, B[7], nullptr, 1, 0, 3);
    // m0 = mixed([s0, aggS0], mid0)                                 // m0 = B6
    M(B[5], B[3], B[4], wtM0, b_mid + 0, g_mid + 0, be_mid + 0,
      w_mid + 0, B[6], nullptr, 0, 0, 4);
    // s0(B5), aggS0(B3,B4) dead

    A(B[7], B[3], B[4]);                                             // aggS1 -> B3,B4

    // m1 = mixed([s1, aggS1], mid1)                                 // m1 = B5
    M(B[7], B[3], B[4], wtM1, b_mid + 384, g_mid + 384, be_mid + 384,
      w_mid + 3, B[5], nullptr, 0, 0, 5);
    // s1(B7), aggS1(B3,B4) dead

    // s_last = mixed([m0, agg m0], last0) + mixed([m1, agg m1], last1)  // sl = B7
    A(B[6], B[3], B[4]);
    M(B[6], B[3], B[4], wtL0, b_last + 0, g_last + 0, be_last + 0,
      w_last + 0, B[7], nullptr, 0, 0, 6);
    A(B[5], B[3], B[4]);
    M(B[5], B[3], B[4], wtL1, b_last + 384, g_last + 384, be_last + 384,
      w_last + 3, B[7], nullptr, 1, 0, 7);

    // out = relu(norm([m0 | m1 | s_last] @ W_cat + b_cat)) directly to fp32
    M(B[6], B[5], B[7], wtC, b_cat, g_cat, be_cat, nullptr,
      nullptr, out, 0, 1, 8);
}